// Round 4
// baseline (599.045 us; speedup 1.0000x reference)
//
#include <hip/hip_runtime.h>
#include <hip/hip_fp16.h>

#define NN 50000
#define NE 1200000
#define DIM 64
#define NB 782            // node buckets of 64: ceil(50000/64)
#define SLICES 512
#define ES 2344           // ceil(NE/SLICES); 512*2344 = 1200128 >= NE
#define VCAP 2048         // vsort bucket cache cap (mean 1536, ~13 sigma)
#define GB 782            // gemm blocks: ceil(NN/64)
#define FRONT_LDS 33792   // max(lsort ~18.3KB, gemm 33.8KB)

// ================= fused front kernel bodies =================

// slice bucket-sort body, two passes (U for degrees, V for CSR build).
// Scan = wave shfl-scan + 4-entry LDS combine (2 barriers, was 16).
__device__ __forceinline__ void lsort_body(char* smem, const int* __restrict__ ei,
                                           ushort* __restrict__ usort,
                                           int* __restrict__ ebuf,
                                           int* __restrict__ lpart_u,
                                           int* __restrict__ lpart_v,
                                           int s) {
    int* hist = (int*)smem;                       // (NB+1)*4 -> pad 3136
    int* wsum = (int*)(smem + 3136);              // 4 ints
    ushort* sbu = (ushort*)(smem + 4160);         // ES*2 = 4688
    int* sbv = (int*)(smem + 8848);               // ES*4 = 9376 -> end 18224
    int t = threadIdx.x;
    int w = t >> 6, l = t & 63;
    int e0 = s * ES, e1 = min(e0 + ES, NE), len = e1 - e0;
    int i0 = t * 4;

    // ======== pass U (degree counting feed: bucket-sorted u values)
    for (int i = t; i < NB; i += 256) hist[i] = 0;
    __syncthreads();
    for (int e = e0 + t; e < e1; e += 256) atomicAdd(&hist[ei[e] >> 6], 1);
    __syncthreads();
    {
        int h0 = (i0 + 0 < NB) ? hist[i0 + 0] : 0;
        int h1 = (i0 + 1 < NB) ? hist[i0 + 1] : 0;
        int h2 = (i0 + 2 < NB) ? hist[i0 + 2] : 0;
        int h3 = (i0 + 3 < NB) ? hist[i0 + 3] : 0;
        int p1 = h0, p2 = h0 + h1, p3 = p2 + h2, p4 = p3 + h3;
        int inc = p4;
        for (int o = 1; o < 64; o <<= 1) {
            int x = __shfl_up(inc, o, 64);
            if (l >= o) inc += x;
        }
        if (l == 63) wsum[w] = inc;
        __syncthreads();
        int base = 0;
#pragma unroll
        for (int j = 0; j < 4; ++j) if (j < w) base += wsum[j];
        int total = wsum[0] + wsum[1] + wsum[2] + wsum[3];
        int excl = base + inc - p4;
        int* lpu = lpart_u + s * (NB + 1);
        if (i0 + 0 < NB) { lpu[i0 + 0] = excl;      hist[i0 + 0] = excl; }
        if (i0 + 1 < NB) { lpu[i0 + 1] = excl + p1; hist[i0 + 1] = excl + p1; }
        if (i0 + 2 < NB) { lpu[i0 + 2] = excl + p2; hist[i0 + 2] = excl + p2; }
        if (i0 + 3 < NB) { lpu[i0 + 3] = excl + p3; hist[i0 + 3] = excl + p3; }
        if (t == 255) lpu[NB] = total;
    }
    __syncthreads();
    for (int e = e0 + t; e < e1; e += 256) {
        int u = ei[e];
        int pos = atomicAdd(&hist[u >> 6], 1);
        sbu[pos] = (ushort)u;
    }
    __syncthreads();
    for (int i = t; i < len; i += 256) usort[e0 + i] = sbu[i];
    for (int i = t; i < NB; i += 256) hist[i] = 0;   // fold V-zeroing into dump phase
    __syncthreads();

    // ======== pass V
    for (int e = e0 + t; e < e1; e += 256) atomicAdd(&hist[ei[NE + e] >> 6], 1);
    __syncthreads();
    {
        int h0 = (i0 + 0 < NB) ? hist[i0 + 0] : 0;
        int h1 = (i0 + 1 < NB) ? hist[i0 + 1] : 0;
        int h2 = (i0 + 2 < NB) ? hist[i0 + 2] : 0;
        int h3 = (i0 + 3 < NB) ? hist[i0 + 3] : 0;
        int p1 = h0, p2 = h0 + h1, p3 = p2 + h2, p4 = p3 + h3;
        int inc = p4;
        for (int o = 1; o < 64; o <<= 1) {
            int x = __shfl_up(inc, o, 64);
            if (l >= o) inc += x;
        }
        if (l == 63) wsum[w] = inc;
        __syncthreads();
        int base = 0;
#pragma unroll
        for (int j = 0; j < 4; ++j) if (j < w) base += wsum[j];
        int total = wsum[0] + wsum[1] + wsum[2] + wsum[3];
        int excl = base + inc - p4;
        int* lpv = lpart_v + s * (NB + 1);
        if (i0 + 0 < NB) { lpv[i0 + 0] = excl;      hist[i0 + 0] = excl; }
        if (i0 + 1 < NB) { lpv[i0 + 1] = excl + p1; hist[i0 + 1] = excl + p1; }
        if (i0 + 2 < NB) { lpv[i0 + 2] = excl + p2; hist[i0 + 2] = excl + p2; }
        if (i0 + 3 < NB) { lpv[i0 + 3] = excl + p3; hist[i0 + 3] = excl + p3; }
        if (t == 255) lpv[NB] = total;
    }
    __syncthreads();
    for (int e = e0 + t; e < e1; e += 256) {
        int u = ei[e], v = ei[NE + e];
        int pos = atomicAdd(&hist[v >> 6], 1);
        sbv[pos] = u | ((v & 63) << 16);
    }
    __syncthreads();
    for (int i = t; i < len; i += 256) ebuf[e0 + i] = sbv[i];
}

// fp32 GEMM body -> fp16 out. smem: As[64][68] | Bs[64][64]
__device__ __forceinline__ void gemm_h_body(char* smem, int blk,
                                            const float* __restrict__ A,
                                            const float* __restrict__ W,
                                            const float* __restrict__ bias,
                                            __half* __restrict__ Ch, int M) {
    float (*As)[68] = (float(*)[68])smem;
    float (*Bs)[64] = (float(*)[64])(smem + 17408);
    int t = threadIdx.x;
    int row0 = blk * 64;
#pragma unroll
    for (int i = 0; i < 4; ++i) {
        int idx = t + i * 256;
        int r = idx >> 4, c = (idx & 15) << 2;
        float4 val = make_float4(0.f, 0.f, 0.f, 0.f);
        if (row0 + r < M) val = *(const float4*)&A[(size_t)(row0 + r) * DIM + c];
        *(float4*)&As[r][c] = val;
        *(float4*)&Bs[r][c] = *(const float4*)&W[r * DIM + c];
    }
    __syncthreads();
    int r0 = (t >> 4) * 4;
    int c0 = (t & 15) * 4;
    float acc[4][4] = {};
#pragma unroll
    for (int k = 0; k < 64; k += 4) {
        float4 b0 = *(float4*)&Bs[k + 0][c0];
        float4 b1 = *(float4*)&Bs[k + 1][c0];
        float4 b2 = *(float4*)&Bs[k + 2][c0];
        float4 b3 = *(float4*)&Bs[k + 3][c0];
#pragma unroll
        for (int i = 0; i < 4; ++i) {
            float4 av = *(float4*)&As[r0 + i][k];
            acc[i][0] = fmaf(av.x, b0.x, fmaf(av.y, b1.x, fmaf(av.z, b2.x, fmaf(av.w, b3.x, acc[i][0]))));
            acc[i][1] = fmaf(av.x, b0.y, fmaf(av.y, b1.y, fmaf(av.z, b2.y, fmaf(av.w, b3.y, acc[i][1]))));
            acc[i][2] = fmaf(av.x, b0.z, fmaf(av.y, b1.z, fmaf(av.z, b2.z, fmaf(av.w, b3.z, acc[i][2]))));
            acc[i][3] = fmaf(av.x, b0.w, fmaf(av.y, b1.w, fmaf(av.z, b2.w, fmaf(av.w, b3.w, acc[i][3]))));
        }
    }
    float4 bv = *(const float4*)&bias[c0];
#pragma unroll
    for (int i = 0; i < 4; ++i) {
        int r = row0 + r0 + i;
        if (r < M) {
            __half2 p0 = __floats2half2_rn(acc[i][0] + bv.x, acc[i][1] + bv.y);
            __half2 p1 = __floats2half2_rn(acc[i][2] + bv.z, acc[i][3] + bv.w);
            uint2 pk;
            pk.x = *(unsigned int*)&p0;
            pk.y = *(unsigned int*)&p1;
            *(uint2*)&Ch[(size_t)r * DIM + c0] = pk;
        }
    }
}

// fused front. Panel-interleaved so each CU's 2 resident blocks are
// 1 sort + 1 GEMM (overlap). No VGPR cap: the sort is ILP-bound
// (R1: capping to 36 VGPR dropped VALUBusy 14.5->5.6% and cost +13 us).
__global__ __launch_bounds__(256) void k_front(const int* __restrict__ ei,
                                               ushort* __restrict__ usort,
                                               int* __restrict__ ebuf,
                                               int* __restrict__ lpart_u,
                                               int* __restrict__ lpart_v,
                                               const float* __restrict__ A,
                                               const float* __restrict__ W,
                                               const float* __restrict__ bias,
                                               __half* __restrict__ Ch) {
    extern __shared__ char smem[];
    int b = blockIdx.x;
    if (b < 256)
        lsort_body(smem, ei, usort, ebuf, lpart_u, lpart_v, b);
    else if (b < 512)
        gemm_h_body(smem, b - 256, A, W, bias, Ch, NN);
    else if (b < 768)
        lsort_body(smem, ei, usort, ebuf, lpart_u, lpart_v, b - 256);
    else
        gemm_h_body(smem, b - 512, A, W, bias, Ch, NN);
}

// ---------------- u-count -> dis. Block per bucket (782 blocks, was 196:
// <0.8 waves/SIMD latency-bound — R3 lesson: widen the starved tail kernels).
__global__ __launch_bounds__(256) void k_mid(const ushort* __restrict__ usort,
                                             const int* __restrict__ lpart_u,
                                             float* __restrict__ dis,
                                             float* __restrict__ colsum) {
    __shared__ int sh[64];
    int b = blockIdx.x;
    int t = threadIdx.x;
    if (b == 0 && t < 64) colsum[t] = 0.f;
    if (t < 64) sh[t] = 0;
    __syncthreads();
    for (int s = t; s < SLICES; s += 256) {
        const int* row = lpart_u + s * (NB + 1);
        int st = row[b], en = row[b + 1];
        for (int i = st; i < en; ++i)
            atomicAdd(&sh[usort[s * ES + i] & 63], 1);
    }
    __syncthreads();
    int n = (b << 6) + t;
    if (t < 64 && n < NN) dis[n] = rsqrtf((float)sh[t] + 1.0f);
}

// ---------------- per-bucket counting sort, block per bucket (4x TLP vs R3).
// rbase(b) = sum_s lpart_v[s][b]; n = sum_s len. Both from the loads the
// cache-fill already needs.
__global__ __launch_bounds__(256) void k_vsort(const int* __restrict__ ebuf,
                                               const int* __restrict__ lpart_v,
                                               const float* __restrict__ dis,
                                               int* __restrict__ edges,
                                               int* __restrict__ row_ptr) {
    __shared__ int cache[VCAP];
    __shared__ int cnt[64];
    __shared__ int cur[64];
    __shared__ int wsum[4];
    __shared__ int rsum[4];
    int t = threadIdx.x, w = t >> 6, l = t & 63;
    int b = blockIdx.x;
    // 2 sub-slices per thread covers all 512 slices
    int s0 = t * 2, s1 = t * 2 + 1;
    const int* r0p = lpart_v + s0 * (NB + 1);
    const int* r1p = lpart_v + s1 * (NB + 1);
    int a0 = r0p[b], a1 = r0p[b + 1];
    int c0 = r1p[b], c1 = r1p[b + 1];
    int len0 = a1 - a0, len1 = c1 - c0;
    int tl = len0 + len1;
    int ts = a0 + c0;
    int inc = tl;
    for (int o = 1; o < 64; o <<= 1) {
        int x = __shfl_up(inc, o, 64);
        if (l >= o) inc += x;
    }
    int tss = ts;
    for (int off = 32; off; off >>= 1) tss += __shfl_down(tss, off, 64);
    if (l == 63) wsum[w] = inc;
    if (l == 0) rsum[w] = tss;
    if (t < 64) cnt[t] = 0;
    __syncthreads();
    int base = 0;
#pragma unroll
    for (int j = 0; j < 4; ++j) if (j < w) base += wsum[j];
    int n = wsum[0] + wsum[1] + wsum[2] + wsum[3];
    int rbase = rsum[0] + rsum[1] + rsum[2] + rsum[3];
    int pos = base + inc - tl;
    if (n <= VCAP) {
        for (int i = 0; i < len0; ++i) cache[pos + i] = ebuf[s0 * ES + a0 + i];
        int pos1 = pos + len0;
        for (int i = 0; i < len1; ++i) cache[pos1 + i] = ebuf[s1 * ES + c0 + i];
        __syncthreads();
        for (int i = t; i < n; i += 256)
            atomicAdd(&cnt[(cache[i] >> 16) & 63], 1);
        __syncthreads();
        if (w == 0) {
            int c = cnt[l];
            int inc2 = c;
            for (int o = 1; o < 64; o <<= 1) {
                int x = __shfl_up(inc2, o, 64);
                if (l >= o) inc2 += x;
            }
            int excl = inc2 - c;
            cur[l] = rbase + excl;
            row_ptr[(b << 6) + l] = rbase + excl;
        }
        __syncthreads();
        for (int i = t; i < n; i += 256) {
            int rec = cache[i];
            int u = rec & 0xFFFF;
            int p2 = atomicAdd(&cur[(rec >> 16) & 63], 1);
            ushort dh = __half_as_ushort(__float2half_rn(dis[u]));
            edges[p2] = u | ((int)dh << 16);
        }
    } else {
        for (int s = t; s < SLICES; s += 256) {
            const int* row = lpart_v + s * (NB + 1);
            int st = row[b], en = row[b + 1];
            for (int i = st; i < en; ++i)
                atomicAdd(&cnt[(ebuf[s * ES + i] >> 16) & 63], 1);
        }
        __syncthreads();
        if (w == 0) {
            int c = cnt[l];
            int inc2 = c;
            for (int o = 1; o < 64; o <<= 1) {
                int x = __shfl_up(inc2, o, 64);
                if (l >= o) inc2 += x;
            }
            int excl = inc2 - c;
            cur[l] = rbase + excl;
            row_ptr[(b << 6) + l] = rbase + excl;
        }
        __syncthreads();
        for (int s = t; s < SLICES; s += 256) {
            const int* row = lpart_v + s * (NB + 1);
            int st = row[b], en = row[b + 1];
            for (int i = st; i < en; ++i) {
                int rec = ebuf[s * ES + i];
                int u = rec & 0xFFFF;
                int p2 = atomicAdd(&cur[(rec >> 16) & 63], 1);
                ushort dh = __half_as_ushort(__float2half_rn(dis[u]));
                edges[p2] = u | ((int)dh << 16);
            }
        }
    }
}

// ---------------- agg phase of the fused agg+GEMM kernels.
// Wave w aggregates nodes row0+w*16 .. +15 into As rows (fp32), same
// 8-lanes/edge 16B-gather structure as the standalone k_agg.
__device__ __forceinline__ void agg_body(float (*As)[68], int (*se)[64],
                                         const uint4* __restrict__ Hq4,
                                         const float* __restrict__ dis,
                                         const int* __restrict__ row_ptr,
                                         const int* __restrict__ edges,
                                         int row0) {
    int t = threadIdx.x;
    int w = t >> 6, l = t & 63;
    int g = l >> 3;           // edge subgroup 0..7
    int p = l & 7;            // feature oct 0..7 (8 fp16 = 16B)
#pragma unroll 1
    for (int nn = 0; nn < 16; ++nn) {
        int node = row0 + (w << 4) + nn;
        int start = 0, num = 0;
        if (node < NN) { start = row_ptr[node]; num = row_ptr[node + 1] - start; }
        float4 a0 = {0.f, 0.f, 0.f, 0.f};
        float4 a1 = {0.f, 0.f, 0.f, 0.f};
        for (int base = 0; base < num; base += 64) {
            int lim = min(64, num - base);
            se[w][l] = (l < lim) ? edges[start + base + l] : 0;
            __builtin_amdgcn_wave_barrier();
            int octs = (lim + 7) >> 3;           // 1..8, wave-uniform
            int rr[8]; uint4 hh[8];
#pragma unroll
            for (int q = 0; q < 8; ++q)
                if (q < octs) rr[q] = se[w][8 * q + g];
#pragma unroll
            for (int q = 0; q < 8; ++q)
                if (q < octs) hh[q] = Hq4[((rr[q] & 0xFFFF) << 3) + p];
#pragma unroll
            for (int q = 0; q < 8; ++q)
                if (q < octs) {
                    float wt = __half2float(__ushort_as_half((ushort)((unsigned)rr[q] >> 16)));
                    float2 f0 = __half22float2(*(const __half2*)&hh[q].x);
                    float2 f1 = __half22float2(*(const __half2*)&hh[q].y);
                    float2 f2 = __half22float2(*(const __half2*)&hh[q].z);
                    float2 f3 = __half22float2(*(const __half2*)&hh[q].w);
                    a0.x = fmaf(wt, f0.x, a0.x);
                    a0.y = fmaf(wt, f0.y, a0.y);
                    a0.z = fmaf(wt, f1.x, a0.z);
                    a0.w = fmaf(wt, f1.y, a0.w);
                    a1.x = fmaf(wt, f2.x, a1.x);
                    a1.y = fmaf(wt, f2.y, a1.y);
                    a1.z = fmaf(wt, f3.x, a1.z);
                    a1.w = fmaf(wt, f3.y, a1.w);
                }
            __builtin_amdgcn_wave_barrier();
        }
#pragma unroll
        for (int m = 8; m < 64; m <<= 1) {
            a0.x += __shfl_xor(a0.x, m, 64);
            a0.y += __shfl_xor(a0.y, m, 64);
            a0.z += __shfl_xor(a0.z, m, 64);
            a0.w += __shfl_xor(a0.w, m, 64);
            a1.x += __shfl_xor(a1.x, m, 64);
            a1.y += __shfl_xor(a1.y, m, 64);
            a1.z += __shfl_xor(a1.z, m, 64);
            a1.w += __shfl_xor(a1.w, m, 64);
        }
        if (g == 0) {
            int r = (w << 4) + nn;
            if (node < NN) {
                uint4 sv = Hq4[(node << 3) + p];
                float2 s0 = __half22float2(*(const __half2*)&sv.x);
                float2 s1 = __half22float2(*(const __half2*)&sv.y);
                float2 s2 = __half22float2(*(const __half2*)&sv.z);
                float2 s3 = __half22float2(*(const __half2*)&sv.w);
                float dv = dis[node];
                float4 o0, o1;
                o0.x = fmaf(dv, a0.x, s0.x);
                o0.y = fmaf(dv, a0.y, s0.y);
                o0.z = fmaf(dv, a0.z, s1.x);
                o0.w = fmaf(dv, a0.w, s1.y);
                o1.x = fmaf(dv, a1.x, s2.x);
                o1.y = fmaf(dv, a1.y, s2.y);
                o1.z = fmaf(dv, a1.z, s3.x);
                o1.w = fmaf(dv, a1.w, s3.y);
                *(float4*)&As[r][p << 3] = o0;
                *(float4*)&As[r][(p << 3) + 4] = o1;
            } else {
                float4 z = {0.f, 0.f, 0.f, 0.f};
                *(float4*)&As[r][p << 3] = z;
                *(float4*)&As[r][(p << 3) + 4] = z;
            }
        }
    }
}

// ---------------- fused agg + dual GEMM: reads Hsrc (gathers), writes
// Hdst = half(relu((agg)@W1+b1)@W2 + b2). Hsrc != Hdst (ping-pong: blocks
// write their own rows while others still gather the old values).
__global__ __launch_bounds__(256) void k_aggemm2(const uint4* __restrict__ Hq4,
                                                 const float* __restrict__ dis,
                                                 const int* __restrict__ row_ptr,
                                                 const int* __restrict__ edges,
                                                 const float* __restrict__ W1,
                                                 const float* __restrict__ b1,
                                                 const float* __restrict__ W2,
                                                 const float* __restrict__ b2,
                                                 __half* __restrict__ Zh) {
    __shared__ float As[64][68];
    __shared__ float Bs[64][64];
    __shared__ int se[4][64];
    int t = threadIdx.x;
    int row0 = blockIdx.x * 64;
    agg_body(As, se, Hq4, dis, row_ptr, edges, row0);
#pragma unroll
    for (int i = 0; i < 4; ++i) {
        int idx = t + i * 256;
        int r = idx >> 4, c = (idx & 15) << 2;
        *(float4*)&Bs[r][c] = *(const float4*)&W1[r * DIM + c];
    }
    __syncthreads();
    int r0 = (t >> 4) * 4;
    int c0 = (t & 15) * 4;
    float acc[4][4] = {};
#pragma unroll
    for (int k = 0; k < 64; k += 4) {
        float4 v0 = *(float4*)&Bs[k + 0][c0];
        float4 v1 = *(float4*)&Bs[k + 1][c0];
        float4 v2 = *(float4*)&Bs[k + 2][c0];
        float4 v3 = *(float4*)&Bs[k + 3][c0];
#pragma unroll
        for (int i = 0; i < 4; ++i) {
            float4 av = *(float4*)&As[r0 + i][k];
            acc[i][0] = fmaf(av.x, v0.x, fmaf(av.y, v1.x, fmaf(av.z, v2.x, fmaf(av.w, v3.x, acc[i][0]))));
            acc[i][1] = fmaf(av.x, v0.y, fmaf(av.y, v1.y, fmaf(av.z, v2.y, fmaf(av.w, v3.y, acc[i][1]))));
            acc[i][2] = fmaf(av.x, v0.z, fmaf(av.y, v1.z, fmaf(av.z, v2.z, fmaf(av.w, v3.z, acc[i][2]))));
            acc[i][3] = fmaf(av.x, v0.w, fmaf(av.y, v1.w, fmaf(av.z, v2.w, fmaf(av.w, v3.w, acc[i][3]))));
        }
    }
    float4 bv1 = *(const float4*)&b1[c0];
    __syncthreads();
#pragma unroll
    for (int i = 0; i < 4; ++i) {
        float4 y;
        y.x = fmaxf(acc[i][0] + bv1.x, 0.f);
        y.y = fmaxf(acc[i][1] + bv1.y, 0.f);
        y.z = fmaxf(acc[i][2] + bv1.z, 0.f);
        y.w = fmaxf(acc[i][3] + bv1.w, 0.f);
        *(float4*)&As[r0 + i][c0] = y;
    }
#pragma unroll
    for (int i = 0; i < 4; ++i) {
        int idx = t + i * 256;
        int r = idx >> 4, c = (idx & 15) << 2;
        *(float4*)&Bs[r][c] = *(const float4*)&W2[r * DIM + c];
    }
    __syncthreads();
    float acc2[4][4] = {};
#pragma unroll
    for (int k = 0; k < 64; k += 4) {
        float4 v0 = *(float4*)&Bs[k + 0][c0];
        float4 v1 = *(float4*)&Bs[k + 1][c0];
        float4 v2 = *(float4*)&Bs[k + 2][c0];
        float4 v3 = *(float4*)&Bs[k + 3][c0];
#pragma unroll
        for (int i = 0; i < 4; ++i) {
            float4 av = *(float4*)&As[r0 + i][k];
            acc2[i][0] = fmaf(av.x, v0.x, fmaf(av.y, v1.x, fmaf(av.z, v2.x, fmaf(av.w, v3.x, acc2[i][0]))));
            acc2[i][1] = fmaf(av.x, v0.y, fmaf(av.y, v1.y, fmaf(av.z, v2.y, fmaf(av.w, v3.y, acc2[i][1]))));
            acc2[i][2] = fmaf(av.x, v0.z, fmaf(av.y, v1.z, fmaf(av.z, v2.z, fmaf(av.w, v3.z, acc2[i][2]))));
            acc2[i][3] = fmaf(av.x, v0.w, fmaf(av.y, v1.w, fmaf(av.z, v2.w, fmaf(av.w, v3.w, acc2[i][3]))));
        }
    }
    float4 bv2 = *(const float4*)&b2[c0];
#pragma unroll
    for (int i = 0; i < 4; ++i) {
        int r = row0 + r0 + i;
        if (r < NN) {
            __half2 p0 = __floats2half2_rn(acc2[i][0] + bv2.x, acc2[i][1] + bv2.y);
            __half2 p1 = __floats2half2_rn(acc2[i][2] + bv2.z, acc2[i][3] + bv2.w);
            uint2 pk;
            pk.x = *(unsigned int*)&p0;
            pk.y = *(unsigned int*)&p1;
            *(uint2*)&Zh[(size_t)r * DIM + c0] = pk;
        }
    }
}

// ---------------- fused agg + last GEMM: relu((agg)@W+b) -> column sums
__global__ __launch_bounds__(256) void k_aggemm_last(const uint4* __restrict__ Hq4,
                                                     const float* __restrict__ dis,
                                                     const int* __restrict__ row_ptr,
                                                     const int* __restrict__ edges,
                                                     const float* __restrict__ W,
                                                     const float* __restrict__ bias,
                                                     float* __restrict__ colsum) {
    __shared__ float As[64][68];
    __shared__ float Bs[64][64];
    __shared__ int se[4][64];
    int t = threadIdx.x;
    int row0 = blockIdx.x * 64;
    agg_body(As, se, Hq4, dis, row_ptr, edges, row0);
#pragma unroll
    for (int i = 0; i < 4; ++i) {
        int idx = t + i * 256;
        int r = idx >> 4, c = (idx & 15) << 2;
        *(float4*)&Bs[r][c] = *(const float4*)&W[r * DIM + c];
    }
    __syncthreads();
    int r0 = (t >> 4) * 4;
    int c0 = (t & 15) * 4;
    float acc[4][4] = {};
#pragma unroll
    for (int k = 0; k < 64; k += 4) {
        float4 b0 = *(float4*)&Bs[k + 0][c0];
        float4 b1 = *(float4*)&Bs[k + 1][c0];
        float4 b2 = *(float4*)&Bs[k + 2][c0];
        float4 b3 = *(float4*)&Bs[k + 3][c0];
#pragma unroll
        for (int i = 0; i < 4; ++i) {
            float4 av = *(float4*)&As[r0 + i][k];
            acc[i][0] = fmaf(av.x, b0.x, fmaf(av.y, b1.x, fmaf(av.z, b2.x, fmaf(av.w, b3.x, acc[i][0]))));
            acc[i][1] = fmaf(av.x, b0.y, fmaf(av.y, b1.y, fmaf(av.z, b2.y, fmaf(av.w, b3.y, acc[i][1]))));
            acc[i][2] = fmaf(av.x, b0.z, fmaf(av.y, b1.z, fmaf(av.z, b2.z, fmaf(av.w, b3.z, acc[i][2]))));
            acc[i][3] = fmaf(av.x, b0.w, fmaf(av.y, b1.w, fmaf(av.z, b2.w, fmaf(av.w, b3.w, acc[i][3]))));
        }
    }
    float4 bv = *(const float4*)&bias[c0];
    float csum[4] = {0.f, 0.f, 0.f, 0.f};
#pragma unroll
    for (int i = 0; i < 4; ++i) {
        int r = row0 + r0 + i;
        if (r < NN) {
            csum[0] += fmaxf(acc[i][0] + bv.x, 0.f);
            csum[1] += fmaxf(acc[i][1] + bv.y, 0.f);
            csum[2] += fmaxf(acc[i][2] + bv.z, 0.f);
            csum[3] += fmaxf(acc[i][3] + bv.w, 0.f);
        }
    }
    float* red = &As[0][0];
    __syncthreads();
    *(float4*)&red[(t >> 4) * 64 + c0] = make_float4(csum[0], csum[1], csum[2], csum[3]);
    __syncthreads();
    if (t < 64) {
        float s = 0.f;
#pragma unroll
        for (int g = 0; g < 16; ++g) s += red[g * 64 + t];
        atomicAdd(&colsum[t], s);
    }
}

// ---------------- readout
__global__ void k_out(const float* __restrict__ colsum, const float* __restrict__ out_w,
                      const float* __restrict__ out_b, float* __restrict__ out) {
    int f = threadIdx.x;
    float v = colsum[f] * (1.0f / (float)NN) * out_w[f];
    for (int off = 32; off; off >>= 1) v += __shfl_down(v, off, 64);
    if (f == 0) out[0] = v + out_b[0];
}

extern "C" void kernel_launch(void* const* d_in, const int* in_sizes, int n_in,
                              void* d_out, int out_size, void* d_ws, size_t ws_size,
                              hipStream_t stream) {
    const float* H  = (const float*)d_in[0];
    const int*   ei = (const int*)d_in[1];
    const float* enc_w[3] = { (const float*)d_in[3], (const float*)d_in[7],  (const float*)d_in[11] };
    const float* enc_b[3] = { (const float*)d_in[4], (const float*)d_in[8],  (const float*)d_in[12] };
    const float* upd_w[3] = { (const float*)d_in[5], (const float*)d_in[9],  (const float*)d_in[13] };
    const float* upd_b[3] = { (const float*)d_in[6], (const float*)d_in[10], (const float*)d_in[14] };
    const float* out_w = (const float*)d_in[15];
    const float* out_b = (const float*)d_in[16];
    float* out = (float*)d_out;

    size_t off = 0;
    auto carve = [&](size_t bytes) {
        void* p = (char*)d_ws + off;
        off = (off + bytes + 255) & ~(size_t)255;
        return p;
    };
    int*    lpart_u = (int*)carve((size_t)SLICES * (NB + 1) * 4);
    int*    lpart_v = (int*)carve((size_t)SLICES * (NB + 1) * 4);
    float*  dis     = (float*)carve((size_t)NN * 4);
    ushort* usort   = (ushort*)carve((size_t)SLICES * ES * 2);
    int*    ebuf    = (int*)carve((size_t)SLICES * ES * 4);
    int*    edges   = (int*)carve((size_t)NE * 4);
    int*    row_ptr = (int*)carve((size_t)(NN + 65) * 4);
    __half* ChA     = (__half*)carve((size_t)NN * DIM * 2);
    __half* ChB     = (__half*)carve((size_t)NN * DIM * 2);
    float*  colsum  = (float*)carve(64 * 4);

    const uint4* HqA = (const uint4*)ChA;
    const uint4* HqB = (const uint4*)ChB;

    // front: 512 slice-sorts + enc-GEMM-0 (-> ChA), panel-interleaved
    k_front<<<512 + GB, 256, FRONT_LDS, stream>>>(ei, usort, ebuf, lpart_u, lpart_v,
                                                  H, enc_w[0], enc_b[0], ChA);
    k_mid<<<NB, 256, 0, stream>>>(usort, lpart_u, dis, colsum);
    k_vsort<<<NB, 256, 0, stream>>>(ebuf, lpart_v, dis, edges, row_ptr);

    // layer 1: gather ChA -> write ChB; layer 2: ChB -> ChA; last: ChA -> colsum
    k_aggemm2<<<GB, 256, 0, stream>>>(HqA, dis, row_ptr, edges,
                                      upd_w[0], upd_b[0], enc_w[1], enc_b[1], ChB);
    k_aggemm2<<<GB, 256, 0, stream>>>(HqB, dis, row_ptr, edges,
                                      upd_w[1], upd_b[1], enc_w[2], enc_b[2], ChA);
    k_aggemm_last<<<GB, 256, 0, stream>>>(HqA, dis, row_ptr, edges,
                                          upd_w[2], upd_b[2], colsum);

    k_out<<<1, 64, 0, stream>>>(colsum, out_w, out_b, out);
}

// Round 5
// 374.578 us; speedup vs baseline: 1.5993x; 1.5993x over previous
//
#include <hip/hip_runtime.h>
#include <hip/hip_fp16.h>

#define NN 50000
#define NE 1200000
#define DIM 64
#define NB 782            // node buckets of 64: ceil(50000/64)
#define SLICES 512
#define ES 2344           // ceil(NE/SLICES); 512*2344 = 1200128 >= NE
#define VCAP 2048         // vsort bucket cache cap (mean 1536, ~13 sigma)
#define GB 782            // gemm blocks: ceil(NN/64)
#define FRONT_LDS 33792   // max(lsort ~18.3KB, gemm 33.8KB)

// ================= fused front kernel bodies =================

// slice bucket-sort body, two passes (U for degrees, V for CSR build).
// Scan = wave shfl-scan + 4-entry LDS combine (2 barriers, was 16).
__device__ __forceinline__ void lsort_body(char* smem, const int* __restrict__ ei,
                                           ushort* __restrict__ usort,
                                           int* __restrict__ ebuf,
                                           int* __restrict__ lpart_u,
                                           int* __restrict__ lpart_v,
                                           int s) {
    int* hist = (int*)smem;                       // (NB+1)*4 -> pad 3136
    int* wsum = (int*)(smem + 3136);              // 4 ints
    ushort* sbu = (ushort*)(smem + 4160);         // ES*2 = 4688
    int* sbv = (int*)(smem + 8848);               // ES*4 = 9376 -> end 18224
    int t = threadIdx.x;
    int w = t >> 6, l = t & 63;
    int e0 = s * ES, e1 = min(e0 + ES, NE), len = e1 - e0;
    int i0 = t * 4;

    // ======== pass U (degree counting feed: bucket-sorted u values)
    for (int i = t; i < NB; i += 256) hist[i] = 0;
    __syncthreads();
    for (int e = e0 + t; e < e1; e += 256) atomicAdd(&hist[ei[e] >> 6], 1);
    __syncthreads();
    {
        int h0 = (i0 + 0 < NB) ? hist[i0 + 0] : 0;
        int h1 = (i0 + 1 < NB) ? hist[i0 + 1] : 0;
        int h2 = (i0 + 2 < NB) ? hist[i0 + 2] : 0;
        int h3 = (i0 + 3 < NB) ? hist[i0 + 3] : 0;
        int p1 = h0, p2 = h0 + h1, p3 = p2 + h2, p4 = p3 + h3;
        int inc = p4;
        for (int o = 1; o < 64; o <<= 1) {
            int x = __shfl_up(inc, o, 64);
            if (l >= o) inc += x;
        }
        if (l == 63) wsum[w] = inc;
        __syncthreads();
        int base = 0;
#pragma unroll
        for (int j = 0; j < 4; ++j) if (j < w) base += wsum[j];
        int total = wsum[0] + wsum[1] + wsum[2] + wsum[3];
        int excl = base + inc - p4;
        int* lpu = lpart_u + s * (NB + 1);
        if (i0 + 0 < NB) { lpu[i0 + 0] = excl;      hist[i0 + 0] = excl; }
        if (i0 + 1 < NB) { lpu[i0 + 1] = excl + p1; hist[i0 + 1] = excl + p1; }
        if (i0 + 2 < NB) { lpu[i0 + 2] = excl + p2; hist[i0 + 2] = excl + p2; }
        if (i0 + 3 < NB) { lpu[i0 + 3] = excl + p3; hist[i0 + 3] = excl + p3; }
        if (t == 255) lpu[NB] = total;
    }
    __syncthreads();
    for (int e = e0 + t; e < e1; e += 256) {
        int u = ei[e];
        int pos = atomicAdd(&hist[u >> 6], 1);
        sbu[pos] = (ushort)u;
    }
    __syncthreads();
    for (int i = t; i < len; i += 256) usort[e0 + i] = sbu[i];
    for (int i = t; i < NB; i += 256) hist[i] = 0;   // fold V-zeroing into dump phase
    __syncthreads();

    // ======== pass V
    for (int e = e0 + t; e < e1; e += 256) atomicAdd(&hist[ei[NE + e] >> 6], 1);
    __syncthreads();
    {
        int h0 = (i0 + 0 < NB) ? hist[i0 + 0] : 0;
        int h1 = (i0 + 1 < NB) ? hist[i0 + 1] : 0;
        int h2 = (i0 + 2 < NB) ? hist[i0 + 2] : 0;
        int h3 = (i0 + 3 < NB) ? hist[i0 + 3] : 0;
        int p1 = h0, p2 = h0 + h1, p3 = p2 + h2, p4 = p3 + h3;
        int inc = p4;
        for (int o = 1; o < 64; o <<= 1) {
            int x = __shfl_up(inc, o, 64);
            if (l >= o) inc += x;
        }
        if (l == 63) wsum[w] = inc;
        __syncthreads();
        int base = 0;
#pragma unroll
        for (int j = 0; j < 4; ++j) if (j < w) base += wsum[j];
        int total = wsum[0] + wsum[1] + wsum[2] + wsum[3];
        int excl = base + inc - p4;
        int* lpv = lpart_v + s * (NB + 1);
        if (i0 + 0 < NB) { lpv[i0 + 0] = excl;      hist[i0 + 0] = excl; }
        if (i0 + 1 < NB) { lpv[i0 + 1] = excl + p1; hist[i0 + 1] = excl + p1; }
        if (i0 + 2 < NB) { lpv[i0 + 2] = excl + p2; hist[i0 + 2] = excl + p2; }
        if (i0 + 3 < NB) { lpv[i0 + 3] = excl + p3; hist[i0 + 3] = excl + p3; }
        if (t == 255) lpv[NB] = total;
    }
    __syncthreads();
    for (int e = e0 + t; e < e1; e += 256) {
        int u = ei[e], v = ei[NE + e];
        int pos = atomicAdd(&hist[v >> 6], 1);
        sbv[pos] = u | ((v & 63) << 16);
    }
    __syncthreads();
    for (int i = t; i < len; i += 256) ebuf[e0 + i] = sbv[i];
}

// fp32 GEMM body -> fp16 out. smem: As[64][68] | Bs[64][64]
__device__ __forceinline__ void gemm_h_body(char* smem, int blk,
                                            const float* __restrict__ A,
                                            const float* __restrict__ W,
                                            const float* __restrict__ bias,
                                            __half* __restrict__ Ch, int M) {
    float (*As)[68] = (float(*)[68])smem;
    float (*Bs)[64] = (float(*)[64])(smem + 17408);
    int t = threadIdx.x;
    int row0 = blk * 64;
#pragma unroll
    for (int i = 0; i < 4; ++i) {
        int idx = t + i * 256;
        int r = idx >> 4, c = (idx & 15) << 2;
        float4 val = make_float4(0.f, 0.f, 0.f, 0.f);
        if (row0 + r < M) val = *(const float4*)&A[(size_t)(row0 + r) * DIM + c];
        *(float4*)&As[r][c] = val;
        *(float4*)&Bs[r][c] = *(const float4*)&W[r * DIM + c];
    }
    __syncthreads();
    int r0 = (t >> 4) * 4;
    int c0 = (t & 15) * 4;
    float acc[4][4] = {};
#pragma unroll
    for (int k = 0; k < 64; k += 4) {
        float4 b0 = *(float4*)&Bs[k + 0][c0];
        float4 b1 = *(float4*)&Bs[k + 1][c0];
        float4 b2 = *(float4*)&Bs[k + 2][c0];
        float4 b3 = *(float4*)&Bs[k + 3][c0];
#pragma unroll
        for (int i = 0; i < 4; ++i) {
            float4 av = *(float4*)&As[r0 + i][k];
            acc[i][0] = fmaf(av.x, b0.x, fmaf(av.y, b1.x, fmaf(av.z, b2.x, fmaf(av.w, b3.x, acc[i][0]))));
            acc[i][1] = fmaf(av.x, b0.y, fmaf(av.y, b1.y, fmaf(av.z, b2.y, fmaf(av.w, b3.y, acc[i][1]))));
            acc[i][2] = fmaf(av.x, b0.z, fmaf(av.y, b1.z, fmaf(av.z, b2.z, fmaf(av.w, b3.z, acc[i][2]))));
            acc[i][3] = fmaf(av.x, b0.w, fmaf(av.y, b1.w, fmaf(av.z, b2.w, fmaf(av.w, b3.w, acc[i][3]))));
        }
    }
    float4 bv = *(const float4*)&bias[c0];
#pragma unroll
    for (int i = 0; i < 4; ++i) {
        int r = row0 + r0 + i;
        if (r < M) {
            __half2 p0 = __floats2half2_rn(acc[i][0] + bv.x, acc[i][1] + bv.y);
            __half2 p1 = __floats2half2_rn(acc[i][2] + bv.z, acc[i][3] + bv.w);
            uint2 pk;
            pk.x = *(unsigned int*)&p0;
            pk.y = *(unsigned int*)&p1;
            *(uint2*)&Ch[(size_t)r * DIM + c0] = pk;
        }
    }
}

// fused front. Panel-interleaved so each CU's 2 resident blocks are
// 1 sort + 1 GEMM (overlap). No VGPR cap: the sort is ILP-bound
// (R1: capping to 36 VGPR dropped VALUBusy 14.5->5.6% and cost +13 us).
__global__ __launch_bounds__(256) void k_front(const int* __restrict__ ei,
                                               ushort* __restrict__ usort,
                                               int* __restrict__ ebuf,
                                               int* __restrict__ lpart_u,
                                               int* __restrict__ lpart_v,
                                               const float* __restrict__ A,
                                               const float* __restrict__ W,
                                               const float* __restrict__ bias,
                                               __half* __restrict__ Ch) {
    extern __shared__ char smem[];
    int b = blockIdx.x;
    if (b < 256)
        lsort_body(smem, ei, usort, ebuf, lpart_u, lpart_v, b);
    else if (b < 512)
        gemm_h_body(smem, b - 256, A, W, bias, Ch, NN);
    else if (b < 768)
        lsort_body(smem, ei, usort, ebuf, lpart_u, lpart_v, b - 256);
    else
        gemm_h_body(smem, b - 512, A, W, bias, Ch, NN);
}

// ---------------- u-count -> dis. Block per bucket (782 blocks; R3's 196-block
// version was <0.8 waves/SIMD latency-starved).
__global__ __launch_bounds__(256) void k_mid(const ushort* __restrict__ usort,
                                             const int* __restrict__ lpart_u,
                                             float* __restrict__ dis,
                                             float* __restrict__ colsum) {
    __shared__ int sh[64];
    int b = blockIdx.x;
    int t = threadIdx.x;
    if (b == 0 && t < 64) colsum[t] = 0.f;
    if (t < 64) sh[t] = 0;
    __syncthreads();
    for (int s = t; s < SLICES; s += 256) {
        const int* row = lpart_u + s * (NB + 1);
        int st = row[b], en = row[b + 1];
        for (int i = st; i < en; ++i)
            atomicAdd(&sh[usort[s * ES + i] & 63], 1);
    }
    __syncthreads();
    int n = (b << 6) + t;
    if (t < 64 && n < NN) dis[n] = rsqrtf((float)sh[t] + 1.0f);
}

// ---------------- per-bucket counting sort, block per bucket (4x TLP vs R3).
// rbase(b) = sum_s lpart_v[s][b]; n = sum_s len. Both from the loads the
// cache-fill already needs.
__global__ __launch_bounds__(256) void k_vsort(const int* __restrict__ ebuf,
                                               const int* __restrict__ lpart_v,
                                               const float* __restrict__ dis,
                                               int* __restrict__ edges,
                                               int* __restrict__ row_ptr) {
    __shared__ int cache[VCAP];
    __shared__ int cnt[64];
    __shared__ int cur[64];
    __shared__ int wsum[4];
    __shared__ int rsum[4];
    int t = threadIdx.x, w = t >> 6, l = t & 63;
    int b = blockIdx.x;
    // 2 sub-slices per thread covers all 512 slices
    int s0 = t * 2, s1 = t * 2 + 1;
    const int* r0p = lpart_v + s0 * (NB + 1);
    const int* r1p = lpart_v + s1 * (NB + 1);
    int a0 = r0p[b], a1 = r0p[b + 1];
    int c0 = r1p[b], c1 = r1p[b + 1];
    int len0 = a1 - a0, len1 = c1 - c0;
    int tl = len0 + len1;
    int ts = a0 + c0;
    int inc = tl;
    for (int o = 1; o < 64; o <<= 1) {
        int x = __shfl_up(inc, o, 64);
        if (l >= o) inc += x;
    }
    int tss = ts;
    for (int off = 32; off; off >>= 1) tss += __shfl_down(tss, off, 64);
    if (l == 63) wsum[w] = inc;
    if (l == 0) rsum[w] = tss;
    if (t < 64) cnt[t] = 0;
    __syncthreads();
    int base = 0;
#pragma unroll
    for (int j = 0; j < 4; ++j) if (j < w) base += wsum[j];
    int n = wsum[0] + wsum[1] + wsum[2] + wsum[3];
    int rbase = rsum[0] + rsum[1] + rsum[2] + rsum[3];
    int pos = base + inc - tl;
    if (n <= VCAP) {
        for (int i = 0; i < len0; ++i) cache[pos + i] = ebuf[s0 * ES + a0 + i];
        int pos1 = pos + len0;
        for (int i = 0; i < len1; ++i) cache[pos1 + i] = ebuf[s1 * ES + c0 + i];
        __syncthreads();
        for (int i = t; i < n; i += 256)
            atomicAdd(&cnt[(cache[i] >> 16) & 63], 1);
        __syncthreads();
        if (w == 0) {
            int c = cnt[l];
            int inc2 = c;
            for (int o = 1; o < 64; o <<= 1) {
                int x = __shfl_up(inc2, o, 64);
                if (l >= o) inc2 += x;
            }
            int excl = inc2 - c;
            cur[l] = rbase + excl;
            row_ptr[(b << 6) + l] = rbase + excl;
        }
        __syncthreads();
        for (int i = t; i < n; i += 256) {
            int rec = cache[i];
            int u = rec & 0xFFFF;
            int p2 = atomicAdd(&cur[(rec >> 16) & 63], 1);
            ushort dh = __half_as_ushort(__float2half_rn(dis[u]));
            edges[p2] = u | ((int)dh << 16);
        }
    } else {
        for (int s = t; s < SLICES; s += 256) {
            const int* row = lpart_v + s * (NB + 1);
            int st = row[b], en = row[b + 1];
            for (int i = st; i < en; ++i)
                atomicAdd(&cnt[(ebuf[s * ES + i] >> 16) & 63], 1);
        }
        __syncthreads();
        if (w == 0) {
            int c = cnt[l];
            int inc2 = c;
            for (int o = 1; o < 64; o <<= 1) {
                int x = __shfl_up(inc2, o, 64);
                if (l >= o) inc2 += x;
            }
            int excl = inc2 - c;
            cur[l] = rbase + excl;
            row_ptr[(b << 6) + l] = rbase + excl;
        }
        __syncthreads();
        for (int s = t; s < SLICES; s += 256) {
            const int* row = lpart_v + s * (NB + 1);
            int st = row[b], en = row[b + 1];
            for (int i = st; i < en; ++i) {
                int rec = ebuf[s * ES + i];
                int u = rec & 0xFFFF;
                int p2 = atomicAdd(&cur[(rec >> 16) & 63], 1);
                ushort dh = __half_as_ushort(__float2half_rn(dis[u]));
                edges[p2] = u | ((int)dh << 16);
            }
        }
    }
}

// ---------------- fused dual GEMM: Zh = half(relu(X@W1+b1)@W2 + b2)
__global__ __launch_bounds__(256) void k_gemm2(const float* __restrict__ X,
                                               const float* __restrict__ W1,
                                               const float* __restrict__ b1,
                                               const float* __restrict__ W2,
                                               const float* __restrict__ b2,
                                               __half* __restrict__ Zh, int M) {
    __shared__ float As[64][68];
    __shared__ float Bs[64][64];
    int t = threadIdx.x;
    int row0 = blockIdx.x * 64;
#pragma unroll
    for (int i = 0; i < 4; ++i) {
        int idx = t + i * 256;
        int r = idx >> 4, c = (idx & 15) << 2;
        float4 val = make_float4(0.f, 0.f, 0.f, 0.f);
        if (row0 + r < M) val = *(const float4*)&X[(size_t)(row0 + r) * DIM + c];
        *(float4*)&As[r][c] = val;
        *(float4*)&Bs[r][c] = *(const float4*)&W1[r * DIM + c];
    }
    __syncthreads();
    int r0 = (t >> 4) * 4;
    int c0 = (t & 15) * 4;
    float acc[4][4] = {};
#pragma unroll
    for (int k = 0; k < 64; k += 4) {
        float4 v0 = *(float4*)&Bs[k + 0][c0];
        float4 v1 = *(float4*)&Bs[k + 1][c0];
        float4 v2 = *(float4*)&Bs[k + 2][c0];
        float4 v3 = *(float4*)&Bs[k + 3][c0];
#pragma unroll
        for (int i = 0; i < 4; ++i) {
            float4 av = *(float4*)&As[r0 + i][k];
            acc[i][0] = fmaf(av.x, v0.x, fmaf(av.y, v1.x, fmaf(av.z, v2.x, fmaf(av.w, v3.x, acc[i][0]))));
            acc[i][1] = fmaf(av.x, v0.y, fmaf(av.y, v1.y, fmaf(av.z, v2.y, fmaf(av.w, v3.y, acc[i][1]))));
            acc[i][2] = fmaf(av.x, v0.z, fmaf(av.y, v1.z, fmaf(av.z, v2.z, fmaf(av.w, v3.z, acc[i][2]))));
            acc[i][3] = fmaf(av.x, v0.w, fmaf(av.y, v1.w, fmaf(av.z, v2.w, fmaf(av.w, v3.w, acc[i][3]))));
        }
    }
    float4 bv1 = *(const float4*)&b1[c0];
    __syncthreads();
#pragma unroll
    for (int i = 0; i < 4; ++i) {
        float4 y;
        y.x = fmaxf(acc[i][0] + bv1.x, 0.f);
        y.y = fmaxf(acc[i][1] + bv1.y, 0.f);
        y.z = fmaxf(acc[i][2] + bv1.z, 0.f);
        y.w = fmaxf(acc[i][3] + bv1.w, 0.f);
        *(float4*)&As[r0 + i][c0] = y;
    }
#pragma unroll
    for (int i = 0; i < 4; ++i) {
        int idx = t + i * 256;
        int r = idx >> 4, c = (idx & 15) << 2;
        *(float4*)&Bs[r][c] = *(const float4*)&W2[r * DIM + c];
    }
    __syncthreads();
    float acc2[4][4] = {};
#pragma unroll
    for (int k = 0; k < 64; k += 4) {
        float4 v0 = *(float4*)&Bs[k + 0][c0];
        float4 v1 = *(float4*)&Bs[k + 1][c0];
        float4 v2 = *(float4*)&Bs[k + 2][c0];
        float4 v3 = *(float4*)&Bs[k + 3][c0];
#pragma unroll
        for (int i = 0; i < 4; ++i) {
            float4 av = *(float4*)&As[r0 + i][k];
            acc2[i][0] = fmaf(av.x, v0.x, fmaf(av.y, v1.x, fmaf(av.z, v2.x, fmaf(av.w, v3.x, acc2[i][0]))));
            acc2[i][1] = fmaf(av.x, v0.y, fmaf(av.y, v1.y, fmaf(av.z, v2.y, fmaf(av.w, v3.y, acc2[i][1]))));
            acc2[i][2] = fmaf(av.x, v0.z, fmaf(av.y, v1.z, fmaf(av.z, v2.z, fmaf(av.w, v3.z, acc2[i][2]))));
            acc2[i][3] = fmaf(av.x, v0.w, fmaf(av.y, v1.w, fmaf(av.z, v2.w, fmaf(av.w, v3.w, acc2[i][3]))));
        }
    }
    float4 bv2 = *(const float4*)&b2[c0];
#pragma unroll
    for (int i = 0; i < 4; ++i) {
        int r = row0 + r0 + i;
        if (r < M) {
            __half2 p0 = __floats2half2_rn(acc2[i][0] + bv2.x, acc2[i][1] + bv2.y);
            __half2 p1 = __floats2half2_rn(acc2[i][2] + bv2.z, acc2[i][3] + bv2.w);
            uint2 pk;
            pk.x = *(unsigned int*)&p0;
            pk.y = *(unsigned int*)&p1;
            *(uint2*)&Zh[(size_t)r * DIM + c0] = pk;
        }
    }
}

// ---------------- last GEMM: relu(X@W+b) -> column sums only
__global__ __launch_bounds__(256) void k_gemm_last(const float* __restrict__ A,
                                                   const float* __restrict__ W,
                                                   const float* __restrict__ bias,
                                                   int M, float* __restrict__ colsum) {
    __shared__ float As[64][68];
    __shared__ float Bs[64][64];
    int t = threadIdx.x;
    int row0 = blockIdx.x * 64;
#pragma unroll
    for (int i = 0; i < 4; ++i) {
        int idx = t + i * 256;
        int r = idx >> 4, c = (idx & 15) << 2;
        float4 val = make_float4(0.f, 0.f, 0.f, 0.f);
        if (row0 + r < M) val = *(const float4*)&A[(size_t)(row0 + r) * DIM + c];
        *(float4*)&As[r][c] = val;
        *(float4*)&Bs[r][c] = *(const float4*)&W[r * DIM + c];
    }
    __syncthreads();
    int r0 = (t >> 4) * 4;
    int c0 = (t & 15) * 4;
    float acc[4][4] = {};
#pragma unroll
    for (int k = 0; k < 64; k += 4) {
        float4 b0 = *(float4*)&Bs[k + 0][c0];
        float4 b1 = *(float4*)&Bs[k + 1][c0];
        float4 b2 = *(float4*)&Bs[k + 2][c0];
        float4 b3 = *(float4*)&Bs[k + 3][c0];
#pragma unroll
        for (int i = 0; i < 4; ++i) {
            float4 av = *(float4*)&As[r0 + i][k];
            acc[i][0] = fmaf(av.x, b0.x, fmaf(av.y, b1.x, fmaf(av.z, b2.x, fmaf(av.w, b3.x, acc[i][0]))));
            acc[i][1] = fmaf(av.x, b0.y, fmaf(av.y, b1.y, fmaf(av.z, b2.y, fmaf(av.w, b3.y, acc[i][1]))));
            acc[i][2] = fmaf(av.x, b0.z, fmaf(av.y, b1.z, fmaf(av.z, b2.z, fmaf(av.w, b3.z, acc[i][2]))));
            acc[i][3] = fmaf(av.x, b0.w, fmaf(av.y, b1.w, fmaf(av.z, b2.w, fmaf(av.w, b3.w, acc[i][3]))));
        }
    }
    float4 bv = *(const float4*)&bias[c0];
    float csum[4] = {0.f, 0.f, 0.f, 0.f};
#pragma unroll
    for (int i = 0; i < 4; ++i) {
        int r = row0 + r0 + i;
        if (r < M) {
            csum[0] += fmaxf(acc[i][0] + bv.x, 0.f);
            csum[1] += fmaxf(acc[i][1] + bv.y, 0.f);
            csum[2] += fmaxf(acc[i][2] + bv.z, 0.f);
            csum[3] += fmaxf(acc[i][3] + bv.w, 0.f);
        }
    }
    float* red = &As[0][0];
    __syncthreads();
    *(float4*)&red[(t >> 4) * 64 + c0] = make_float4(csum[0], csum[1], csum[2], csum[3]);
    __syncthreads();
    if (t < 64) {
        float s = 0.f;
#pragma unroll
        for (int g = 0; g < 16; ++g) s += red[g * 64 + t];
        atomicAdd(&colsum[t], s);
    }
}

// ---------------- aggregation: wave per node, 8 lanes/edge with 16B gathers.
// Standalone (12500 blocks): R4 proved fusing this under the GEMM tile
// (782 blocks, 16 nodes serialized per wave) costs 4x — gather lives on TLP.
__global__ __launch_bounds__(256) void k_agg(const uint4* __restrict__ Hq4,
                                             const float* __restrict__ dis,
                                             const int* __restrict__ row_ptr,
                                             const int* __restrict__ edges,
                                             float* __restrict__ X) {
    __shared__ int se[4][64];
    int w = threadIdx.x >> 6, l = threadIdx.x & 63;
    int node = (blockIdx.x << 2) + w;
    if (node >= NN) return;
    int start = row_ptr[node];
    int num = row_ptr[node + 1] - start;
    int g = l >> 3;           // edge subgroup 0..7
    int p = l & 7;            // feature oct 0..7 (8 fp16 = 16B)
    float4 a0 = {0.f, 0.f, 0.f, 0.f};
    float4 a1 = {0.f, 0.f, 0.f, 0.f};
    for (int base = 0; base < num; base += 64) {
        int lim = min(64, num - base);
        se[w][l] = (l < lim) ? edges[start + base + l] : 0;
        __builtin_amdgcn_wave_barrier();
        int octs = (lim + 7) >> 3;           // 1..8, wave-uniform
        int rr[8]; uint4 hh[8];
#pragma unroll
        for (int q = 0; q < 8; ++q)
            if (q < octs) rr[q] = se[w][8 * q + g];
#pragma unroll
        for (int q = 0; q < 8; ++q)
            if (q < octs) hh[q] = Hq4[((rr[q] & 0xFFFF) << 3) + p];
#pragma unroll
        for (int q = 0; q < 8; ++q)
            if (q < octs) {
                float wt = __half2float(__ushort_as_half((ushort)((unsigned)rr[q] >> 16)));
                float2 f0 = __half22float2(*(const __half2*)&hh[q].x);
                float2 f1 = __half22float2(*(const __half2*)&hh[q].y);
                float2 f2 = __half22float2(*(const __half2*)&hh[q].z);
                float2 f3 = __half22float2(*(const __half2*)&hh[q].w);
                a0.x = fmaf(wt, f0.x, a0.x);
                a0.y = fmaf(wt, f0.y, a0.y);
                a0.z = fmaf(wt, f1.x, a0.z);
                a0.w = fmaf(wt, f1.y, a0.w);
                a1.x = fmaf(wt, f2.x, a1.x);
                a1.y = fmaf(wt, f2.y, a1.y);
                a1.z = fmaf(wt, f3.x, a1.z);
                a1.w = fmaf(wt, f3.y, a1.w);
            }
        __builtin_amdgcn_wave_barrier();
    }
#pragma unroll
    for (int m = 8; m < 64; m <<= 1) {
        a0.x += __shfl_xor(a0.x, m, 64);
        a0.y += __shfl_xor(a0.y, m, 64);
        a0.z += __shfl_xor(a0.z, m, 64);
        a0.w += __shfl_xor(a0.w, m, 64);
        a1.x += __shfl_xor(a1.x, m, 64);
        a1.y += __shfl_xor(a1.y, m, 64);
        a1.z += __shfl_xor(a1.z, m, 64);
        a1.w += __shfl_xor(a1.w, m, 64);
    }
    if (g == 0) {
        uint4 sv = Hq4[(node << 3) + p];
        float2 s0 = __half22float2(*(const __half2*)&sv.x);
        float2 s1 = __half22float2(*(const __half2*)&sv.y);
        float2 s2 = __half22float2(*(const __half2*)&sv.z);
        float2 s3 = __half22float2(*(const __half2*)&sv.w);
        float dv = dis[node];
        float4 o0, o1;
        o0.x = fmaf(dv, a0.x, s0.x);
        o0.y = fmaf(dv, a0.y, s0.y);
        o0.z = fmaf(dv, a0.z, s1.x);
        o0.w = fmaf(dv, a0.w, s1.y);
        o1.x = fmaf(dv, a1.x, s2.x);
        o1.y = fmaf(dv, a1.y, s2.y);
        o1.z = fmaf(dv, a1.z, s3.x);
        o1.w = fmaf(dv, a1.w, s3.y);
        float* xr = &X[((size_t)node << 6) + (p << 3)];
        *(float4*)xr = o0;
        *(float4*)(xr + 4) = o1;
    }
}

// ---------------- readout
__global__ void k_out(const float* __restrict__ colsum, const float* __restrict__ out_w,
                      const float* __restrict__ out_b, float* __restrict__ out) {
    int f = threadIdx.x;
    float v = colsum[f] * (1.0f / (float)NN) * out_w[f];
    for (int off = 32; off; off >>= 1) v += __shfl_down(v, off, 64);
    if (f == 0) out[0] = v + out_b[0];
}

extern "C" void kernel_launch(void* const* d_in, const int* in_sizes, int n_in,
                              void* d_out, int out_size, void* d_ws, size_t ws_size,
                              hipStream_t stream) {
    const float* H  = (const float*)d_in[0];
    const int*   ei = (const int*)d_in[1];
    const float* enc_w[3] = { (const float*)d_in[3], (const float*)d_in[7],  (const float*)d_in[11] };
    const float* enc_b[3] = { (const float*)d_in[4], (const float*)d_in[8],  (const float*)d_in[12] };
    const float* upd_w[3] = { (const float*)d_in[5], (const float*)d_in[9],  (const float*)d_in[13] };
    const float* upd_b[3] = { (const float*)d_in[6], (const float*)d_in[10], (const float*)d_in[14] };
    const float* out_w = (const float*)d_in[15];
    const float* out_b = (const float*)d_in[16];
    float* out = (float*)d_out;

    size_t off = 0;
    auto carve = [&](size_t bytes) {
        void* p = (char*)d_ws + off;
        off = (off + bytes + 255) & ~(size_t)255;
        return p;
    };
    int*    lpart_u = (int*)carve((size_t)SLICES * (NB + 1) * 4);
    int*    lpart_v = (int*)carve((size_t)SLICES * (NB + 1) * 4);
    float*  dis     = (float*)carve((size_t)NN * 4);
    ushort* usort   = (ushort*)carve((size_t)SLICES * ES * 2);
    int*    ebuf    = (int*)carve((size_t)SLICES * ES * 4);
    int*    edges   = (int*)carve((size_t)NE * 4);
    int*    row_ptr = (int*)carve((size_t)(NN + 65) * 4);
    __half* Ch      = (__half*)carve((size_t)NN * DIM * 2);
    float*  X       = (float*)carve((size_t)NN * DIM * 4);
    float*  colsum  = (float*)carve(64 * 4);

    const int AB = (NN + 3) / 4;     // 12500
    const uint4* Hq4 = (const uint4*)Ch;

    // front: 512 slice-sorts + enc-GEMM-0, panel-interleaved for co-residency
    k_front<<<512 + GB, 256, FRONT_LDS, stream>>>(ei, usort, ebuf, lpart_u, lpart_v,
                                                  H, enc_w[0], enc_b[0], Ch);
    k_mid<<<NB, 256, 0, stream>>>(usort, lpart_u, dis, colsum);
    k_vsort<<<NB, 256, 0, stream>>>(ebuf, lpart_v, dis, edges, row_ptr);

    k_agg<<<AB, 256, 0, stream>>>(Hq4, dis, row_ptr, edges, X);
    k_gemm2<<<GB, 256, 0, stream>>>(X, upd_w[0], upd_b[0], enc_w[1], enc_b[1], Ch, NN);
    k_agg<<<AB, 256, 0, stream>>>(Hq4, dis, row_ptr, edges, X);
    k_gemm2<<<GB, 256, 0, stream>>>(X, upd_w[1], upd_b[1], enc_w[2], enc_b[2], Ch, NN);
    k_agg<<<AB, 256, 0, stream>>>(Hq4, dis, row_ptr, edges, X);
    k_gemm_last<<<GB, 256, 0, stream>>>(X, upd_w[2], upd_b[2], NN, colsum);

    k_out<<<1, 64, 0, stream>>>(colsum, out_w, out_b, out);
}